// Round 3
// baseline (762.353 us; speedup 1.0000x reference)
//
#include <hip/hip_runtime.h>

// WaveNet block: B=16, C=256, T=4096, LAYERS=8, K=2 (causal, dilation 2^l).
// Stacked single-GEMM per layer: filter+gate rows interleaved at 16-row
// granularity (M=512), N=B*T, K=512. BM=256 x BN=256, BK=32, 8 waves.
// T4 pipeline: raw s_barrier + counted s_waitcnt vmcnt(4) -- next slab's
// global_load_lds stay in flight across the barrier (never drain to 0).
// LDS swizzle uses row bits 2:1 (chunk = quad ^ ((l16>>1)&3)): 8 bank
// groups x depth 2 per 16-lane phase group (old row-parity-aliased form
// was 4 groups x depth 4 -> 3.5M conflict cycles).
// Zout deferred: layers write bf16 Zs chain; final kernel sums 8 Zs in fp32.

typedef __attribute__((ext_vector_type(8))) short s16x8;
typedef __attribute__((ext_vector_type(4))) short s16x4;
typedef __attribute__((ext_vector_type(4))) float f32x4;

#define NB 16
#define NC 256
#define NT 4096
#define TPAD 4224   // 128 (zero pad) + 4096
#define PADT 128
#define NLAYERS 8
#define KTOT 512    // C * Ktap
#define MSTK 512    // stacked rows: f/g interleaved at 16-row granularity

__device__ __forceinline__ short f2bf(float x) {
  union { float f; unsigned u; } v; v.f = x;
  unsigned u = v.u;
  unsigned r = (u + 0x7fffu + ((u >> 16) & 1u)) >> 16;  // RNE
  return (short)r;
}
__device__ __forceinline__ float bf2f(short s) {
  union { float f; unsigned u; } v; v.u = ((unsigned)(unsigned short)s) << 16;
  return v.f;
}

__device__ __forceinline__ void async16(short* lp, const short* gp) {
  __builtin_amdgcn_global_load_lds(
      (const __attribute__((address_space(1))) unsigned int*)gp,
      (__attribute__((address_space(3))) unsigned int*)lp,
      16, 0, 0);
}

// ---------------- prep kernels ----------------

// zero the t<0 pad region of nbuf consecutive X buffers (ws is poisoned 0xAA)
__global__ void zero_pads(short* __restrict__ base, int nbuf, size_t strideSh) {
  int idx = blockIdx.x * 256 + threadIdx.x;    // over nbuf * NB*PADT*NC
  if (idx >= nbuf * NB * PADT * NC) return;
  int j = idx >> 19;                            // / (NB*PADT*NC = 524288)
  int rem = idx & 524287;
  int b = rem >> 15;                            // / (PADT*NC)
  int r2 = rem & 32767;
  base[(size_t)j * strideSh + (size_t)b * TPAD * NC + r2] = 0;
}

// ys [b][c][t] fp32  ->  X0 [b][128+t][c] bf16 (LDS-tiled transpose)
__global__ void transpose_cast(const float* __restrict__ ys, short* __restrict__ X0) {
  __shared__ float tile[64][65];
  const int b = blockIdx.z, c0 = blockIdx.y * 64, t0 = blockIdx.x * 64;
  const int tid = threadIdx.x;
#pragma unroll
  for (int i = 0; i < 16; ++i) {
    int c = (tid >> 6) + i * 4;
    int t = tid & 63;
    tile[c][t] = ys[((size_t)(b * NC + c0 + c)) * NT + t0 + t];
  }
  __syncthreads();
#pragma unroll
  for (int i = 0; i < 2; ++i) {
    int q = tid + i * 256;                      // 512 chunks of 8 bf16
    int t = q >> 3, cc = (q & 7) * 8;
    s16x8 v;
#pragma unroll
    for (int j = 0; j < 8; ++j) v[j] = f2bf(tile[cc + j][t]);
    *(s16x8*)&X0[((size_t)(b * TPAD + PADT + t0 + t)) * NC + c0 + cc] = v;
  }
}

// weights [l][co][ci][kw] fp32 -> stacked interleaved Ws[l][r][k] bf16
// r = j*32 + s*16 + c16  (channel = j*16+c16, s: 0=filter 1=gate), k = kw*256+ci
__global__ void convert_w(const float* __restrict__ fw, const float* __restrict__ gw,
                          short* __restrict__ Ws) {
  int idx = blockIdx.x * 256 + threadIdx.x;     // over 8*512*512 = 2097152
  if (idx >= NLAYERS * MSTK * KTOT) return;
  int k = idx & (KTOT - 1);
  int r = (idx >> 9) & (MSTK - 1);
  int l = idx >> 18;
  int kw = k >> 8, ci = k & 255;
  int j = r >> 5, s = (r >> 4) & 1, c16 = r & 15;
  int ch = j * 16 + c16;
  int src = ((l * NC + ch) * NC + ci) * 2 + kw;
  Ws[idx] = f2bf(s ? gw[src] : fw[src]);
}

// ---------------- fused layer kernel ----------------
// grid (2, 16, 16): m-tile (128 channels, f+g stacked), t-tile (256), batch.
// 512 threads = 8 waves (2M x 4N). BK=32, double-buffered counted-vmcnt pipe.
__global__ __launch_bounds__(512, 2)
void wavenet_layer(const short* __restrict__ Xin, short* __restrict__ Xout,
                   const short* __restrict__ Wl,
                   const float* __restrict__ bia_f, const float* __restrict__ bia_g,
                   float* __restrict__ Zout, int d, int zmode, int writeX) {
  __shared__ short lds[32768];                  // 64 KB: A0 A1 B0 B1 (16 KB each)

  const int tid = threadIdx.x;
  const int wave = tid >> 6, lane = tid & 63;
  const int quad = lane >> 4, l16 = lane & 15;
  const int wm = wave >> 2, wn = wave & 3;

  // XCD swizzle: hw-consecutive-8 blocks spread over XCDs; remap so the
  // (mt=0, mt=1) pair of one (t,b) tile lands on the same XCD (shared X).
  int flat = blockIdx.x + 2 * (blockIdx.y + 16 * blockIdx.z);   // 0..511
  int swz = (flat & 7) * 64 + (flat >> 3);                      // bijective
  const int mt = swz & 1;
  const int ty = (swz >> 1) & 15;
  const int b  = swz >> 5;
  const int m0s = mt * 256;                     // stacked-row base
  const int t0  = ty * 256;

  const short* Wm = Wl + (size_t)m0s * KTOT;
  const short* Xb = Xin + ((size_t)b * TPAD + PADT + t0) * NC;

  f32x4 acc[8][4] = {};
  // read-side swizzled chunk: row bits 2:1 (NOT bit0 -- that aliases the
  // row-parity bank bit and collapses a 16-lane phase group to 4 groups)
  const int xo = (quad ^ ((l16 >> 1) & 3)) * 8;

  // stage one BK=32 K-slab (A: 256x32, B: 256x32) into buffer `buf`
  auto STAGE = [&](int buf, int kk) {
    short* Ad = lds + buf * 8192;
    short* Bd = lds + 16384 + buf * 8192;
    const int kw = kk >> 3;
    const int ci0 = (kk & 7) * 32;
    const int k0 = kw * 256 + ci0;
    const int tsh = (kw == 0) ? -d : 0;         // tap 0 reads x[t-d]
#pragma unroll
    for (int i = 0; i < 2; ++i) {
      int q = (i * 8 + wave) * 64 + lane;       // physical chunk 0..1023
      int r = q >> 2;                           // row 0..255
      int kc = ((q & 3) ^ ((r >> 1) & 3)) * 8;  // swizzled source chunk
      async16(Ad + q * 8, Wm + r * KTOT + k0 + kc);
      async16(Bd + q * 8, Xb + (r + tsh) * NC + ci0 + kc);   // int arith: tsh<0 ok
    }
  };

  // prologue: fill both buffers; wait only for buf0 (buf1 stays in flight)
  STAGE(0, 0);
  STAGE(1, 1);
  asm volatile("s_waitcnt vmcnt(4)" ::: "memory");
  __builtin_amdgcn_sched_barrier(0);
  __builtin_amdgcn_s_barrier();

  int cur = 0;
#pragma unroll 2
  for (int kk = 0; kk < 16; ++kk) {             // K = 512, BK = 32
    const short* Ar = lds + cur * 8192;
    const short* Br = lds + 16384 + cur * 8192;
    s16x8 bfr[4];
#pragma unroll
    for (int ni = 0; ni < 4; ++ni)
      bfr[ni] = *(const s16x8*)&Br[(wn * 64 + ni * 16 + l16) * 32 + xo];
    __builtin_amdgcn_s_setprio(1);
#pragma unroll
    for (int mi = 0; mi < 8; ++mi) {
      s16x8 af = *(const s16x8*)&Ar[(wm * 128 + mi * 16 + l16) * 32 + xo];
#pragma unroll
      for (int ni = 0; ni < 4; ++ni)
        acc[mi][ni] = __builtin_amdgcn_mfma_f32_16x16x32_bf16(af, bfr[ni], acc[mi][ni], 0, 0, 0);
    }
    __builtin_amdgcn_s_setprio(0);
    if (kk == 15) break;
    asm volatile("s_waitcnt lgkmcnt(0)" ::: "memory");
    __builtin_amdgcn_sched_barrier(0);
    __builtin_amdgcn_s_barrier();               // all waves done reading cur
    __builtin_amdgcn_sched_barrier(0);
    if (kk < 14) {
      STAGE(cur, kk + 2);                       // overwrite cur with slab kk+2
      asm volatile("s_waitcnt vmcnt(4)" ::: "memory");  // slab kk+1 landed
    } else {
      asm volatile("s_waitcnt vmcnt(0)" ::: "memory");  // tail: slab 15 landed
    }
    __builtin_amdgcn_sched_barrier(0);
    __builtin_amdgcn_s_barrier();               // cur^1 ready for all waves
    __builtin_amdgcn_sched_barrier(0);
    cur ^= 1;
  }
  __syncthreads();                              // all LDS reads done; reuse as ZT

  // ---------------- epilogue ----------------
  // mi even = filter rows, mi odd = gate rows of the SAME channels (in-thread).
  short* ZT = lds;                              // reuse: [256 t][128 c] rotated

#pragma unroll
  for (int p = 0; p < 4; ++p) {
    const int cloc = (wm * 4 + p) * 16 + quad * 4;   // local channel base
    const int ch = mt * 128 + cloc;                  // global channel base
    float4 bf4 = *(const float4*)&bia_f[ch];
    float4 bg4 = *(const float4*)&bia_g[ch];
    const float* bfp = (const float*)&bf4;
    const float* bgp = (const float*)&bg4;
#pragma unroll
    for (int ni = 0; ni < 4; ++ni) {
      const int tl = wn * 64 + ni * 16 + l16;        // tile-local time
      const int t = t0 + tl;
      short pk[4];
#pragma unroll
      for (int r = 0; r < 4; ++r) {
        float f = acc[2 * p][ni][r] + bfp[r];
        float g = acc[2 * p + 1][ni][r] + bgp[r];
        float ef = __expf(2.f * f);
        float th = 1.f - 2.f / (ef + 1.f);           // tanh, no-overflow form
        float sg = 1.f / (1.f + __expf(-g));
        float z = th * sg;
        if (zmode) {
          size_t zo = ((size_t)(b * NC + ch + r)) * NT + t;
          if (zmode == 1) Zout[zo] = z; else Zout[zo] += z;
        }
        pk[r] = f2bf(z);
      }
      if (writeX) {
        // rotate-swizzle: physical col = (c + t*8) & 127 (stays 4-aligned)
        short* dst = &ZT[tl * 128 + ((cloc + tl * 8) & 127)];
        *(s16x4*)dst = (s16x4){pk[0], pk[1], pk[2], pk[3]};
      }
    }
  }
  if (writeX) {
    __syncthreads();
#pragma unroll
    for (int i = 0; i < 8; ++i) {                // 4096 chunks of 16B (256 t rows)
      int q = tid + i * 512;
      int t = q >> 4, cc = (q & 15) * 8;
      s16x8 v = *(const s16x8*)&ZT[t * 128 + ((cc + t * 8) & 127)];
      *(s16x8*)&Xout[((size_t)(b * TPAD + PADT + t0 + t)) * NC + mt * 128 + cc] = v;
    }
  }
}

// ---------------- final sum + transpose ----------------
// Zout[b][c][t] fp32 = sum over l=1..8 of buf_l[b][128+t][c] (bf16)
__global__ void sum_transpose(const short* __restrict__ base, size_t strideSh,
                              float* __restrict__ Zout) {
  __shared__ float tile[64][65];
  const int b = blockIdx.z, c0 = blockIdx.y * 64, t0 = blockIdx.x * 64;
  const int tid = threadIdx.x;
  float acc[2][8] = {};
#pragma unroll
  for (int l = 1; l <= NLAYERS; ++l) {
    const short* buf = base + (size_t)l * strideSh;
#pragma unroll
    for (int j = 0; j < 2; ++j) {
      int chunk = tid + j * 256;                // 512 chunks of 8 bf16
      int tl = chunk >> 3, cc = (chunk & 7) * 8;
      s16x8 v = *(const s16x8*)&buf[((size_t)(b * TPAD + PADT + t0 + tl)) * NC + c0 + cc];
#pragma unroll
      for (int e = 0; e < 8; ++e) acc[j][e] += bf2f(v[e]);
    }
  }
#pragma unroll
  for (int j = 0; j < 2; ++j) {
    int chunk = tid + j * 256;
    int tl = chunk >> 3, cc = (chunk & 7) * 8;
#pragma unroll
    for (int e = 0; e < 8; ++e) tile[tl][cc + e] = acc[j][e];
  }
  __syncthreads();
#pragma unroll
  for (int i = 0; i < 4; ++i) {
    int c = (tid >> 4) + i * 16;
    int t = (tid & 15) * 4;
    float4 v = make_float4(tile[t][c], tile[t + 1][c], tile[t + 2][c], tile[t + 3][c]);
    *(float4*)&Zout[((size_t)(b * NC + c0 + c)) * NT + t0 + t] = v;
  }
}

// ---------------- launch ----------------
extern "C" void kernel_launch(void* const* d_in, const int* in_sizes, int n_in,
                              void* d_out, int out_size, void* d_ws, size_t ws_size,
                              hipStream_t stream) {
  const float* ys = (const float*)d_in[0];
  const float* fw = (const float*)d_in[1];
  const float* fb = (const float*)d_in[2];
  const float* gw = (const float*)d_in[3];
  const float* gb = (const float*)d_in[4];
  float* Zout = (float*)d_out;

  char* ws = (char*)d_ws;
  const size_t xbytes = (size_t)NB * TPAD * NC * 2;      // 34.6 MB each
  const size_t strideSh = xbytes / 2;
  const size_t wcount = (size_t)NLAYERS * MSTK * KTOT;   // stacked tensor
  const size_t need = 9 * xbytes + wcount * 2;

  const bool deferred = (ws_size >= need);

  short* Xbase = (short*)ws;
  short* Ws;
  if (deferred) Ws = (short*)(ws + 9 * xbytes);
  else          Ws = (short*)(ws + 2 * xbytes);

  {
    int nbuf = deferred ? 8 : 2;
    int total = nbuf * NB * PADT * NC;
    hipLaunchKernelGGL(zero_pads, dim3((total + 255) / 256), dim3(256), 0, stream,
                       Xbase, nbuf, strideSh);
  }
  hipLaunchKernelGGL(transpose_cast, dim3(64, 4, 16), dim3(256), 0, stream, ys, Xbase);
  hipLaunchKernelGGL(convert_w, dim3(8192), dim3(256), 0, stream, fw, gw, Ws);

  for (int l = 0; l < NLAYERS; ++l) {
    const short* Xin;
    short* Xo;
    int zmode, writeX;
    if (deferred) {
      Xin = Xbase + (size_t)l * strideSh;
      Xo = Xbase + (size_t)(l + 1) * strideSh;
      zmode = 0;
      writeX = 1;
    } else {
      Xin = (l & 1) ? Xbase + strideSh : Xbase;
      Xo = (l & 1) ? Xbase : Xbase + strideSh;
      zmode = (l == 0) ? 1 : 2;
      writeX = (l < NLAYERS - 1) ? 1 : 0;
    }
    hipLaunchKernelGGL(wavenet_layer, dim3(2, 16, 16), dim3(512), 0, stream,
                       Xin, Xo,
                       Ws + (size_t)l * MSTK * KTOT,
                       fb + l * NC, gb + l * NC, Zout, 1 << l, zmode, writeX);
  }
  if (deferred) {
    hipLaunchKernelGGL(sum_transpose, dim3(64, 4, 16), dim3(256), 0, stream,
                       Xbase, strideSh, Zout);
  }
}

// Round 4
// 719.432 us; speedup vs baseline: 1.0597x; 1.0597x over previous
//
#include <hip/hip_runtime.h>

// WaveNet block: B=16, C=256, T=4096, LAYERS=8, K=2 (causal, dilation 2^l).
// Stacked single-GEMM per layer: filter+gate rows interleaved at 16-row
// granularity (M=512), N=B*T, K=512. BM=256 x BN=256, BK=32, 8 waves,
// counted-vmcnt double-buffered K-loop (never drains to 0 mid-loop).
// KEY (r4): Zout accumulation moved off the scatter path. Counters showed
// deferred never ran (ws < 315 MB) -- every layer did a 4B-scalar fp32
// rmw into Zout[b][c][t] at 16KB stride = the 75% epilogue cost.
// Now: fp32 Zacc[b][t][c] (same layout as the ZT tile) rmw'd with
// coalesced float4 in the ZT readback loop. Tiers by ws_size:
//   B: Zacc in ws (ws >= 2X+W+64MB)  -> final transpose to Zout
//   C: Zacc aliased on d_out (ws >= 2X+W, guaranteed) -> transpose into
//      freed X area, copy back
//   D: legacy scatter fallback (kept for safety)

typedef __attribute__((ext_vector_type(8))) short s16x8;
typedef __attribute__((ext_vector_type(4))) short s16x4;
typedef __attribute__((ext_vector_type(4))) float f32x4;

#define NB 16
#define NC 256
#define NT 4096
#define TPAD 4224   // 128 (zero pad) + 4096
#define PADT 128
#define NLAYERS 8
#define KTOT 512    // C * Ktap
#define MSTK 512    // stacked rows: f/g interleaved at 16-row granularity

__device__ __forceinline__ short f2bf(float x) {
  union { float f; unsigned u; } v; v.f = x;
  unsigned u = v.u;
  unsigned r = (u + 0x7fffu + ((u >> 16) & 1u)) >> 16;  // RNE
  return (short)r;
}
__device__ __forceinline__ float bf2f(short s) {
  union { float f; unsigned u; } v; v.u = ((unsigned)(unsigned short)s) << 16;
  return v.f;
}

__device__ __forceinline__ void async16(short* lp, const short* gp) {
  __builtin_amdgcn_global_load_lds(
      (const __attribute__((address_space(1))) unsigned int*)gp,
      (__attribute__((address_space(3))) unsigned int*)lp,
      16, 0, 0);
}

// ---------------- prep kernels ----------------

// zero the t<0 pad region of nbuf consecutive X buffers (ws is poisoned 0xAA)
__global__ void zero_pads(short* __restrict__ base, int nbuf, size_t strideSh) {
  int idx = blockIdx.x * 256 + threadIdx.x;    // over nbuf * NB*PADT*NC
  if (idx >= nbuf * NB * PADT * NC) return;
  int j = idx >> 19;                            // / (NB*PADT*NC = 524288)
  int rem = idx & 524287;
  int b = rem >> 15;                            // / (PADT*NC)
  int r2 = rem & 32767;
  base[(size_t)j * strideSh + (size_t)b * TPAD * NC + r2] = 0;
}

// ys [b][c][t] fp32  ->  X0 [b][128+t][c] bf16 (LDS-tiled transpose)
__global__ void transpose_cast(const float* __restrict__ ys, short* __restrict__ X0) {
  __shared__ float tile[64][65];
  const int b = blockIdx.z, c0 = blockIdx.y * 64, t0 = blockIdx.x * 64;
  const int tid = threadIdx.x;
#pragma unroll
  for (int i = 0; i < 16; ++i) {
    int c = (tid >> 6) + i * 4;
    int t = tid & 63;
    tile[c][t] = ys[((size_t)(b * NC + c0 + c)) * NT + t0 + t];
  }
  __syncthreads();
#pragma unroll
  for (int i = 0; i < 2; ++i) {
    int q = tid + i * 256;                      // 512 chunks of 8 bf16
    int t = q >> 3, cc = (q & 7) * 8;
    s16x8 v;
#pragma unroll
    for (int j = 0; j < 8; ++j) v[j] = f2bf(tile[cc + j][t]);
    *(s16x8*)&X0[((size_t)(b * TPAD + PADT + t0 + t)) * NC + c0 + cc] = v;
  }
}

// weights [l][co][ci][kw] fp32 -> stacked interleaved Ws[l][r][k] bf16
// r = j*32 + s*16 + c16  (channel = j*16+c16, s: 0=filter 1=gate), k = kw*256+ci
__global__ void convert_w(const float* __restrict__ fw, const float* __restrict__ gw,
                          short* __restrict__ Ws) {
  int idx = blockIdx.x * 256 + threadIdx.x;     // over 8*512*512 = 2097152
  if (idx >= NLAYERS * MSTK * KTOT) return;
  int k = idx & (KTOT - 1);
  int r = (idx >> 9) & (MSTK - 1);
  int l = idx >> 18;
  int kw = k >> 8, ci = k & 255;
  int j = r >> 5, s = (r >> 4) & 1, c16 = r & 15;
  int ch = j * 16 + c16;
  int src = ((l * NC + ch) * NC + ci) * 2 + kw;
  Ws[idx] = f2bf(s ? gw[src] : fw[src]);
}

// ---------------- fused layer kernel ----------------
// grid (2, 16, 16): m-tile (128 channels, f+g stacked), t-tile (256), batch.
// 512 threads = 8 waves (2M x 4N). BK=32, double-buffered counted-vmcnt pipe.
// zmode: 1 = Zacc[b][t][c] store, 2 = Zacc rmw (coalesced, in ZT readback);
//        3 = legacy Zout[b][c][t] scatter store, 4 = legacy scatter rmw.
__global__ __launch_bounds__(512, 2)
void wavenet_layer(const short* __restrict__ Xin, short* __restrict__ Xout,
                   const short* __restrict__ Wl,
                   const float* __restrict__ bia_f, const float* __restrict__ bia_g,
                   float* __restrict__ Z, int d, int zmode, int writeX) {
  __shared__ short lds[32768];                  // 64 KB: A0 A1 B0 B1 (16 KB each)

  const int tid = threadIdx.x;
  const int wave = tid >> 6, lane = tid & 63;
  const int quad = lane >> 4, l16 = lane & 15;
  const int wm = wave >> 2, wn = wave & 3;

  // XCD swizzle: hw-consecutive-8 blocks spread over XCDs; remap so the
  // (mt=0, mt=1) pair of one (t,b) tile lands on the same XCD (shared X).
  int flat = blockIdx.x + 2 * (blockIdx.y + 16 * blockIdx.z);   // 0..511
  int swz = (flat & 7) * 64 + (flat >> 3);                      // bijective
  const int mt = swz & 1;
  const int ty = (swz >> 1) & 15;
  const int b  = swz >> 5;
  const int m0s = mt * 256;                     // stacked-row base
  const int t0  = ty * 256;

  const short* Wm = Wl + (size_t)m0s * KTOT;
  const short* Xb = Xin + ((size_t)b * TPAD + PADT + t0) * NC;

  f32x4 acc[8][4] = {};
  // read-side swizzled chunk: row bits 2:1 (bit0 aliases the row-parity
  // bank bit and collapses a 16-lane phase group to 4 bank groups)
  const int xo = (quad ^ ((l16 >> 1) & 3)) * 8;

  // stage one BK=32 K-slab (A: 256x32, B: 256x32) into buffer `buf`
  auto STAGE = [&](int buf, int kk) {
    short* Ad = lds + buf * 8192;
    short* Bd = lds + 16384 + buf * 8192;
    const int kw = kk >> 3;
    const int ci0 = (kk & 7) * 32;
    const int k0 = kw * 256 + ci0;
    const int tsh = (kw == 0) ? -d : 0;         // tap 0 reads x[t-d]
#pragma unroll
    for (int i = 0; i < 2; ++i) {
      int q = (i * 8 + wave) * 64 + lane;       // physical chunk 0..1023
      int r = q >> 2;                           // row 0..255
      int kc = ((q & 3) ^ ((r >> 1) & 3)) * 8;  // swizzled source chunk
      async16(Ad + q * 8, Wm + r * KTOT + k0 + kc);
      async16(Bd + q * 8, Xb + (r + tsh) * NC + ci0 + kc);   // int arith: tsh<0 ok
    }
  };

  // prologue: fill both buffers; wait only for buf0 (buf1 stays in flight)
  STAGE(0, 0);
  STAGE(1, 1);
  asm volatile("s_waitcnt vmcnt(4)" ::: "memory");
  __builtin_amdgcn_sched_barrier(0);
  __builtin_amdgcn_s_barrier();

  int cur = 0;
#pragma unroll 2
  for (int kk = 0; kk < 16; ++kk) {             // K = 512, BK = 32
    const short* Ar = lds + cur * 8192;
    const short* Br = lds + 16384 + cur * 8192;
    s16x8 bfr[4];
#pragma unroll
    for (int ni = 0; ni < 4; ++ni)
      bfr[ni] = *(const s16x8*)&Br[(wn * 64 + ni * 16 + l16) * 32 + xo];
    __builtin_amdgcn_s_setprio(1);
#pragma unroll
    for (int mi = 0; mi < 8; ++mi) {
      s16x8 af = *(const s16x8*)&Ar[(wm * 128 + mi * 16 + l16) * 32 + xo];
#pragma unroll
      for (int ni = 0; ni < 4; ++ni)
        acc[mi][ni] = __builtin_amdgcn_mfma_f32_16x16x32_bf16(af, bfr[ni], acc[mi][ni], 0, 0, 0);
    }
    __builtin_amdgcn_s_setprio(0);
    if (kk == 15) break;
    asm volatile("s_waitcnt lgkmcnt(0)" ::: "memory");
    __builtin_amdgcn_sched_barrier(0);
    __builtin_amdgcn_s_barrier();               // all waves done reading cur
    __builtin_amdgcn_sched_barrier(0);
    if (kk < 14) {
      STAGE(cur, kk + 2);                       // overwrite cur with slab kk+2
      asm volatile("s_waitcnt vmcnt(4)" ::: "memory");  // slab kk+1 landed
    } else {
      asm volatile("s_waitcnt vmcnt(0)" ::: "memory");  // tail: slab 15 landed
    }
    __builtin_amdgcn_sched_barrier(0);
    __builtin_amdgcn_s_barrier();               // cur^1 ready for all waves
    __builtin_amdgcn_sched_barrier(0);
    cur ^= 1;
  }
  __syncthreads();                              // all LDS reads done; reuse as ZT

  // ---------------- epilogue ----------------
  // mi even = filter rows, mi odd = gate rows of the SAME channels (in-thread).
  const int zacc = (zmode == 1 || zmode == 2);
  const int stageZT = (writeX || zacc);
  short* ZT = lds;                              // reuse: [256 t][128 c] rotated

#pragma unroll
  for (int p = 0; p < 4; ++p) {
    const int cloc = (wm * 4 + p) * 16 + quad * 4;   // local channel base
    const int ch = mt * 128 + cloc;                  // global channel base
    float4 bf4 = *(const float4*)&bia_f[ch];
    float4 bg4 = *(const float4*)&bia_g[ch];
    const float* bfp = (const float*)&bf4;
    const float* bgp = (const float*)&bg4;
#pragma unroll
    for (int ni = 0; ni < 4; ++ni) {
      const int tl = wn * 64 + ni * 16 + l16;        // tile-local time
      const int t = t0 + tl;
      short pk[4];
#pragma unroll
      for (int r = 0; r < 4; ++r) {
        float f = acc[2 * p][ni][r] + bfp[r];
        float g = acc[2 * p + 1][ni][r] + bgp[r];
        float ef = __expf(2.f * f);
        float th = 1.f - 2.f / (ef + 1.f);           // tanh, no-overflow form
        float sg = 1.f / (1.f + __expf(-g));
        float z = th * sg;
        if (zmode >= 3) {                            // legacy scatter path
          size_t zo = ((size_t)(b * NC + ch + r)) * NT + t;
          if (zmode == 3) Z[zo] = z; else Z[zo] += z;
        }
        pk[r] = f2bf(z);
      }
      if (stageZT) {
        // rotate-swizzle: physical col = (c + t*8) & 127 (stays 4-aligned)
        short* dst = &ZT[tl * 128 + ((cloc + tl * 8) & 127)];
        *(s16x4*)dst = (s16x4){pk[0], pk[1], pk[2], pk[3]};
      }
    }
  }
  if (stageZT) {
    __syncthreads();
#pragma unroll
    for (int i = 0; i < 8; ++i) {                // 4096 chunks of 16B (256 t rows)
      int q = tid + i * 512;
      int t = q >> 4, cc = (q & 15) * 8;
      s16x8 v = *(const s16x8*)&ZT[t * 128 + ((cc + t * 8) & 127)];
      if (writeX)
        *(s16x8*)&Xout[((size_t)(b * TPAD + PADT + t0 + t)) * NC + mt * 128 + cc] = v;
      if (zacc) {
        size_t zo = ((size_t)b * NT + t0 + t) * NC + mt * 128 + cc;
        float zv[8];
#pragma unroll
        for (int j = 0; j < 8; ++j) zv[j] = bf2f(v[j]);
        if (zmode == 2) {
          float4 a0 = *(const float4*)&Z[zo];
          float4 a1 = *(const float4*)&Z[zo + 4];
          zv[0] += a0.x; zv[1] += a0.y; zv[2] += a0.z; zv[3] += a0.w;
          zv[4] += a1.x; zv[5] += a1.y; zv[6] += a1.z; zv[7] += a1.w;
        }
        *(float4*)&Z[zo]     = make_float4(zv[0], zv[1], zv[2], zv[3]);
        *(float4*)&Z[zo + 4] = make_float4(zv[4], zv[5], zv[6], zv[7]);
      }
    }
  }
}

// ---------------- final: Zacc [b][t][c] fp32 -> dst [b][c][t] fp32 ----------------
__global__ void transpose_out(const float* __restrict__ src, float* __restrict__ dst) {
  __shared__ float tile[64][65];
  const int b = blockIdx.z, c0 = blockIdx.y * 64, t0 = blockIdx.x * 64;
  const int tid = threadIdx.x;
#pragma unroll
  for (int i = 0; i < 4; ++i) {
    int q = tid + i * 256;                      // 1024 float4 chunks
    int t = q >> 4, c = (q & 15) * 4;
    float4 v = *(const float4*)&src[((size_t)b * NT + t0 + t) * NC + c0 + c];
    tile[t][c] = v.x; tile[t][c + 1] = v.y; tile[t][c + 2] = v.z; tile[t][c + 3] = v.w;
  }
  __syncthreads();
#pragma unroll
  for (int i = 0; i < 4; ++i) {
    int q = tid + i * 256;
    int c = q >> 4, t = (q & 15) * 4;
    float4 v = make_float4(tile[t][c], tile[t + 1][c], tile[t + 2][c], tile[t + 3][c]);
    *(float4*)&dst[((size_t)b * NC + c0 + c) * NT + t0 + t] = v;
  }
}

__global__ void copy4(const float4* __restrict__ s, float4* __restrict__ d, int n) {
  int i = blockIdx.x * 256 + threadIdx.x;
  int stride = gridDim.x * 256;
  for (; i < n; i += stride) d[i] = s[i];
}

// ---------------- launch ----------------
extern "C" void kernel_launch(void* const* d_in, const int* in_sizes, int n_in,
                              void* d_out, int out_size, void* d_ws, size_t ws_size,
                              hipStream_t stream) {
  const float* ys = (const float*)d_in[0];
  const float* fw = (const float*)d_in[1];
  const float* fb = (const float*)d_in[2];
  const float* gw = (const float*)d_in[3];
  const float* gb = (const float*)d_in[4];
  float* Zout = (float*)d_out;

  char* ws = (char*)d_ws;
  const size_t xbytes = (size_t)NB * TPAD * NC * 2;      // 34.6 MB each
  const size_t strideSh = xbytes / 2;                    // shorts per X buffer
  const size_t wbytes = (size_t)NLAYERS * MSTK * KTOT * 2;   // 4.2 MB
  const size_t zbytes = (size_t)NB * NC * NT * 4;        // 64 MB fp32 Zacc

  // tier 1 (B): Zacc in ws.  tier 2 (C): Zacc aliased on d_out, final
  // transpose into freed X area + copy back.  tier 3 (D): legacy scatter.
  int tier;
  if (ws_size >= 2 * xbytes + wbytes + zbytes)      tier = 1;
  else if (ws_size >= 2 * xbytes + wbytes)          tier = 2;
  else                                              tier = 3;

  short* Xbase = (short*)ws;
  short* Ws = (short*)(ws + 2 * xbytes);
  float* Zacc = (tier == 1) ? (float*)(ws + 2 * xbytes + wbytes) : Zout;

  {
    int total = 2 * NB * PADT * NC;
    hipLaunchKernelGGL(zero_pads, dim3((total + 255) / 256), dim3(256), 0, stream,
                       Xbase, 2, strideSh);
  }
  hipLaunchKernelGGL(transpose_cast, dim3(64, 4, 16), dim3(256), 0, stream, ys, Xbase);
  hipLaunchKernelGGL(convert_w, dim3(8192), dim3(256), 0, stream, fw, gw, Ws);

  for (int l = 0; l < NLAYERS; ++l) {
    const short* Xin = (l & 1) ? Xbase + strideSh : Xbase;
    short* Xo       = (l & 1) ? Xbase : Xbase + strideSh;
    int writeX = (l < NLAYERS - 1) ? 1 : 0;
    int zmode;
    float* Zp;
    if (tier <= 2) { zmode = (l == 0) ? 1 : 2; Zp = Zacc; }
    else           { zmode = (l == 0) ? 3 : 4; Zp = Zout; }
    hipLaunchKernelGGL(wavenet_layer, dim3(2, 16, 16), dim3(512), 0, stream,
                       Xin, Xo,
                       Ws + (size_t)l * MSTK * KTOT,
                       fb + l * NC, gb + l * NC, Zp, 1 << l, zmode, writeX);
  }

  if (tier == 1) {
    hipLaunchKernelGGL(transpose_out, dim3(64, 4, 16), dim3(256), 0, stream,
                       Zacc, Zout);
  } else if (tier == 2) {
    // Zacc lives in d_out; transpose into the freed X ping-pong area (fp32,
    // 69.2 MB >= 64 MB), then copy back to d_out.
    float* tmp = (float*)ws;
    hipLaunchKernelGGL(transpose_out, dim3(64, 4, 16), dim3(256), 0, stream,
                       Zacc, tmp);
    int n4 = (int)(zbytes / 16);
    hipLaunchKernelGGL(copy4, dim3(2048), dim3(256), 0, stream,
                       (const float4*)tmp, (float4*)Zout, n4);
  }
}

// Round 5
// 663.646 us; speedup vs baseline: 1.1487x; 1.0841x over previous
//
#include <hip/hip_runtime.h>

// WaveNet block: B=16, C=256, T=4096, LAYERS=8, K=2 (causal, dilation 2^l).
// Stacked single-GEMM per layer: filter+gate rows interleaved at 16-row
// granularity (M=512), N=B*T, K=512. BM=256 x BN=256, BK=32, 8 waves,
// counted-vmcnt double-buffered K-loop (never drains to 0 mid-loop).
// KEY (r5): pair-folded Z accumulation. Layer l+1's Xin IS z_l (bf16), so
// even layers write NO Z traffic; odd layers fold z_l (re-read of their own
// Xin tile, L2-hot) + z_{l+1} into one Zacc rmw. Zacc HBM writes halve
// (8x64 -> 4x64 MB); l=1 is a pure store. Rounding identical to before
// (each contribution passes through bf16 exactly once).
// Tiers: 1 = Zacc in ws; 2 = Zacc aliased on d_out (+transpose/copy tail);
// 3 = legacy per-layer scatter fallback.

typedef __attribute__((ext_vector_type(8))) short s16x8;
typedef __attribute__((ext_vector_type(4))) short s16x4;
typedef __attribute__((ext_vector_type(4))) float f32x4;

#define NB 16
#define NC 256
#define NT 4096
#define TPAD 4224   // 128 (zero pad) + 4096
#define PADT 128
#define NLAYERS 8
#define KTOT 512    // C * Ktap
#define MSTK 512    // stacked rows: f/g interleaved at 16-row granularity

__device__ __forceinline__ short f2bf(float x) {
  union { float f; unsigned u; } v; v.f = x;
  unsigned u = v.u;
  unsigned r = (u + 0x7fffu + ((u >> 16) & 1u)) >> 16;  // RNE
  return (short)r;
}
__device__ __forceinline__ float bf2f(short s) {
  union { float f; unsigned u; } v; v.u = ((unsigned)(unsigned short)s) << 16;
  return v.f;
}

__device__ __forceinline__ void async16(short* lp, const short* gp) {
  __builtin_amdgcn_global_load_lds(
      (const __attribute__((address_space(1))) unsigned int*)gp,
      (__attribute__((address_space(3))) unsigned int*)lp,
      16, 0, 0);
}

// ---------------- prep kernels ----------------

// zero the t<0 pad region of nbuf consecutive X buffers (ws is poisoned 0xAA)
__global__ void zero_pads(short* __restrict__ base, int nbuf, size_t strideSh) {
  int idx = blockIdx.x * 256 + threadIdx.x;    // over nbuf * NB*PADT*NC
  if (idx >= nbuf * NB * PADT * NC) return;
  int j = idx >> 19;                            // / (NB*PADT*NC = 524288)
  int rem = idx & 524287;
  int b = rem >> 15;                            // / (PADT*NC)
  int r2 = rem & 32767;
  base[(size_t)j * strideSh + (size_t)b * TPAD * NC + r2] = 0;
}

// ys [b][c][t] fp32  ->  X0 [b][128+t][c] bf16 (LDS-tiled transpose)
__global__ void transpose_cast(const float* __restrict__ ys, short* __restrict__ X0) {
  __shared__ float tile[64][65];
  const int b = blockIdx.z, c0 = blockIdx.y * 64, t0 = blockIdx.x * 64;
  const int tid = threadIdx.x;
#pragma unroll
  for (int i = 0; i < 16; ++i) {
    int c = (tid >> 6) + i * 4;
    int t = tid & 63;
    tile[c][t] = ys[((size_t)(b * NC + c0 + c)) * NT + t0 + t];
  }
  __syncthreads();
#pragma unroll
  for (int i = 0; i < 2; ++i) {
    int q = tid + i * 256;                      // 512 chunks of 8 bf16
    int t = q >> 3, cc = (q & 7) * 8;
    s16x8 v;
#pragma unroll
    for (int j = 0; j < 8; ++j) v[j] = f2bf(tile[cc + j][t]);
    *(s16x8*)&X0[((size_t)(b * TPAD + PADT + t0 + t)) * NC + c0 + cc] = v;
  }
}

// weights [l][co][ci][kw] fp32 -> stacked interleaved Ws[l][r][k] bf16
// r = j*32 + s*16 + c16  (channel = j*16+c16, s: 0=filter 1=gate), k = kw*256+ci
__global__ void convert_w(const float* __restrict__ fw, const float* __restrict__ gw,
                          short* __restrict__ Ws) {
  int idx = blockIdx.x * 256 + threadIdx.x;     // over 8*512*512 = 2097152
  if (idx >= NLAYERS * MSTK * KTOT) return;
  int k = idx & (KTOT - 1);
  int r = (idx >> 9) & (MSTK - 1);
  int l = idx >> 18;
  int kw = k >> 8, ci = k & 255;
  int j = r >> 5, s = (r >> 4) & 1, c16 = r & 15;
  int ch = j * 16 + c16;
  int src = ((l * NC + ch) * NC + ci) * 2 + kw;
  Ws[idx] = f2bf(s ? gw[src] : fw[src]);
}

// ---------------- fused layer kernel ----------------
// grid (2, 16, 16): m-tile (128 channels, f+g stacked), t-tile (256), batch.
// 512 threads = 8 waves (2M x 4N). BK=32, double-buffered counted-vmcnt pipe.
// zmode: 0 = no Z traffic (even layers);
//        1 = Zacc[b][t][c]  = bf2f(Xin)+z  (l=1, pure store);
//        2 = Zacc[b][t][c] += bf2f(Xin)+z  (l=3,5,7);
//        3/4 = legacy Zout[b][c][t] scatter store/rmw (fallback tier).
__global__ __launch_bounds__(512, 2)
void wavenet_layer(const short* __restrict__ Xin, short* __restrict__ Xout,
                   const short* __restrict__ Wl,
                   const float* __restrict__ bia_f, const float* __restrict__ bia_g,
                   float* __restrict__ Z, int d, int zmode, int writeX) {
  __shared__ short lds[32768];                  // 64 KB: A0 A1 B0 B1 (16 KB each)

  const int tid = threadIdx.x;
  const int wave = tid >> 6, lane = tid & 63;
  const int quad = lane >> 4, l16 = lane & 15;
  const int wm = wave >> 2, wn = wave & 3;

  // XCD swizzle: hw-consecutive-8 blocks spread over XCDs; remap so the
  // (mt=0, mt=1) pair of one (t,b) tile lands on the same XCD (shared X).
  int flat = blockIdx.x + 2 * (blockIdx.y + 16 * blockIdx.z);   // 0..511
  int swz = (flat & 7) * 64 + (flat >> 3);                      // bijective
  const int mt = swz & 1;
  const int ty = (swz >> 1) & 15;
  const int b  = swz >> 5;
  const int m0s = mt * 256;                     // stacked-row base
  const int t0  = ty * 256;

  const short* Wm = Wl + (size_t)m0s * KTOT;
  const short* Xb = Xin + ((size_t)b * TPAD + PADT + t0) * NC;

  f32x4 acc[8][4] = {};
  // read-side swizzled chunk: row bits 2:1 (bit0 aliases the row-parity
  // bank bit and collapses a 16-lane phase group to 4 bank groups)
  const int xo = (quad ^ ((l16 >> 1) & 3)) * 8;

  // stage one BK=32 K-slab (A: 256x32, B: 256x32) into buffer `buf`
  auto STAGE = [&](int buf, int kk) {
    short* Ad = lds + buf * 8192;
    short* Bd = lds + 16384 + buf * 8192;
    const int kw = kk >> 3;
    const int ci0 = (kk & 7) * 32;
    const int k0 = kw * 256 + ci0;
    const int tsh = (kw == 0) ? -d : 0;         // tap 0 reads x[t-d]
#pragma unroll
    for (int i = 0; i < 2; ++i) {
      int q = (i * 8 + wave) * 64 + lane;       // physical chunk 0..1023
      int r = q >> 2;                           // row 0..255
      int kc = ((q & 3) ^ ((r >> 1) & 3)) * 8;  // swizzled source chunk
      async16(Ad + q * 8, Wm + r * KTOT + k0 + kc);
      async16(Bd + q * 8, Xb + (r + tsh) * NC + ci0 + kc);   // int arith: tsh<0 ok
    }
  };

  // prologue: fill both buffers; wait only for buf0 (buf1 stays in flight)
  STAGE(0, 0);
  STAGE(1, 1);
  asm volatile("s_waitcnt vmcnt(4)" ::: "memory");
  __builtin_amdgcn_sched_barrier(0);
  __builtin_amdgcn_s_barrier();

  int cur = 0;
#pragma unroll 2
  for (int kk = 0; kk < 16; ++kk) {             // K = 512, BK = 32
    const short* Ar = lds + cur * 8192;
    const short* Br = lds + 16384 + cur * 8192;
    s16x8 bfr[4];
#pragma unroll
    for (int ni = 0; ni < 4; ++ni)
      bfr[ni] = *(const s16x8*)&Br[(wn * 64 + ni * 16 + l16) * 32 + xo];
    __builtin_amdgcn_s_setprio(1);
#pragma unroll
    for (int mi = 0; mi < 8; ++mi) {
      s16x8 af = *(const s16x8*)&Ar[(wm * 128 + mi * 16 + l16) * 32 + xo];
#pragma unroll
      for (int ni = 0; ni < 4; ++ni)
        acc[mi][ni] = __builtin_amdgcn_mfma_f32_16x16x32_bf16(af, bfr[ni], acc[mi][ni], 0, 0, 0);
    }
    __builtin_amdgcn_s_setprio(0);
    if (kk == 15) break;
    asm volatile("s_waitcnt lgkmcnt(0)" ::: "memory");
    __builtin_amdgcn_sched_barrier(0);
    __builtin_amdgcn_s_barrier();               // all waves done reading cur
    __builtin_amdgcn_sched_barrier(0);
    if (kk < 14) {
      STAGE(cur, kk + 2);                       // overwrite cur with slab kk+2
      asm volatile("s_waitcnt vmcnt(4)" ::: "memory");  // slab kk+1 landed
    } else {
      asm volatile("s_waitcnt vmcnt(0)" ::: "memory");  // tail: slab 15 landed
    }
    __builtin_amdgcn_sched_barrier(0);
    __builtin_amdgcn_s_barrier();               // cur^1 ready for all waves
    __builtin_amdgcn_sched_barrier(0);
    cur ^= 1;
  }
  __syncthreads();                              // all LDS reads done; reuse as ZT

  // ---------------- epilogue ----------------
  // mi even = filter rows, mi odd = gate rows of the SAME channels (in-thread).
  const int zacc = (zmode == 1 || zmode == 2);
  const int stageZT = (writeX || zacc);
  short* ZT = lds;                              // reuse: [256 t][128 c] rotated

#pragma unroll
  for (int p = 0; p < 4; ++p) {
    const int cloc = (wm * 4 + p) * 16 + quad * 4;   // local channel base
    const int ch = mt * 128 + cloc;                  // global channel base
    float4 bf4 = *(const float4*)&bia_f[ch];
    float4 bg4 = *(const float4*)&bia_g[ch];
    const float* bfp = (const float*)&bf4;
    const float* bgp = (const float*)&bg4;
#pragma unroll
    for (int ni = 0; ni < 4; ++ni) {
      const int tl = wn * 64 + ni * 16 + l16;        // tile-local time
      const int t = t0 + tl;
      short pk[4];
#pragma unroll
      for (int r = 0; r < 4; ++r) {
        float f = acc[2 * p][ni][r] + bfp[r];
        float g = acc[2 * p + 1][ni][r] + bgp[r];
        float ef = __expf(2.f * f);
        float th = 1.f - 2.f / (ef + 1.f);           // tanh, no-overflow form
        float sg = 1.f / (1.f + __expf(-g));
        float z = th * sg;
        if (zmode >= 3) {                            // legacy scatter path
          size_t zo = ((size_t)(b * NC + ch + r)) * NT + t;
          if (zmode == 3) Z[zo] = z; else Z[zo] += z;
        }
        pk[r] = f2bf(z);
      }
      if (stageZT) {
        // rotate-swizzle: physical col = (c + t*8) & 127 (stays 4-aligned)
        short* dst = &ZT[tl * 128 + ((cloc + tl * 8) & 127)];
        *(s16x4*)dst = (s16x4){pk[0], pk[1], pk[2], pk[3]};
      }
    }
  }
  if (stageZT) {
    __syncthreads();
#pragma unroll
    for (int i = 0; i < 8; ++i) {                // 4096 chunks of 16B (256 t rows)
      int q = tid + i * 512;
      int t = q >> 4, cc = (q & 15) * 8;
      s16x8 v = *(const s16x8*)&ZT[t * 128 + ((cc + t * 8) & 127)];
      if (writeX)
        *(s16x8*)&Xout[((size_t)(b * TPAD + PADT + t0 + t)) * NC + mt * 128 + cc] = v;
      if (zacc) {
        // fold the PREVIOUS layer's z (= this layer's Xin, L2-hot) + this z
        s16x8 xv = *(const s16x8*)&Xin[((size_t)(b * TPAD + PADT + t0 + t)) * NC + mt * 128 + cc];
        size_t zo = ((size_t)b * NT + t0 + t) * NC + mt * 128 + cc;
        float zv[8];
#pragma unroll
        for (int j = 0; j < 8; ++j) zv[j] = bf2f(v[j]) + bf2f(xv[j]);
        if (zmode == 2) {
          float4 a0 = *(const float4*)&Z[zo];
          float4 a1 = *(const float4*)&Z[zo + 4];
          zv[0] += a0.x; zv[1] += a0.y; zv[2] += a0.z; zv[3] += a0.w;
          zv[4] += a1.x; zv[5] += a1.y; zv[6] += a1.z; zv[7] += a1.w;
        }
        *(float4*)&Z[zo]     = make_float4(zv[0], zv[1], zv[2], zv[3]);
        *(float4*)&Z[zo + 4] = make_float4(zv[4], zv[5], zv[6], zv[7]);
      }
    }
  }
}

// ---------------- final: Zacc [b][t][c] fp32 -> dst [b][c][t] fp32 ----------------
__global__ void transpose_out(const float* __restrict__ src, float* __restrict__ dst) {
  __shared__ float tile[64][65];
  const int b = blockIdx.z, c0 = blockIdx.y * 64, t0 = blockIdx.x * 64;
  const int tid = threadIdx.x;
#pragma unroll
  for (int i = 0; i < 4; ++i) {
    int q = tid + i * 256;                      // 1024 float4 chunks
    int t = q >> 4, c = (q & 15) * 4;
    float4 v = *(const float4*)&src[((size_t)b * NT + t0 + t) * NC + c0 + c];
    tile[t][c] = v.x; tile[t][c + 1] = v.y; tile[t][c + 2] = v.z; tile[t][c + 3] = v.w;
  }
  __syncthreads();
#pragma unroll
  for (int i = 0; i < 4; ++i) {
    int q = tid + i * 256;
    int c = q >> 4, t = (q & 15) * 4;
    float4 v = make_float4(tile[t][c], tile[t + 1][c], tile[t + 2][c], tile[t + 3][c]);
    *(float4*)&dst[((size_t)b * NC + c0 + c) * NT + t0 + t] = v;
  }
}

__global__ void copy4(const float4* __restrict__ s, float4* __restrict__ d, int n) {
  int i = blockIdx.x * 256 + threadIdx.x;
  int stride = gridDim.x * 256;
  for (; i < n; i += stride) d[i] = s[i];
}

// ---------------- launch ----------------
extern "C" void kernel_launch(void* const* d_in, const int* in_sizes, int n_in,
                              void* d_out, int out_size, void* d_ws, size_t ws_size,
                              hipStream_t stream) {
  const float* ys = (const float*)d_in[0];
  const float* fw = (const float*)d_in[1];
  const float* fb = (const float*)d_in[2];
  const float* gw = (const float*)d_in[3];
  const float* gb = (const float*)d_in[4];
  float* Zout = (float*)d_out;

  char* ws = (char*)d_ws;
  const size_t xbytes = (size_t)NB * TPAD * NC * 2;      // 34.6 MB each
  const size_t strideSh = xbytes / 2;                    // shorts per X buffer
  const size_t wbytes = (size_t)NLAYERS * MSTK * KTOT * 2;   // 4.2 MB
  const size_t zbytes = (size_t)NB * NC * NT * 4;        // 64 MB fp32 Zacc

  // tier 1: Zacc in ws.  tier 2: Zacc aliased on d_out, final transpose into
  // freed X area + copy back.  tier 3: legacy scatter.
  int tier;
  if (ws_size >= 2 * xbytes + wbytes + zbytes)      tier = 1;
  else if (ws_size >= 2 * xbytes + wbytes)          tier = 2;
  else                                              tier = 3;

  short* Xbase = (short*)ws;
  short* Ws = (short*)(ws + 2 * xbytes);
  float* Zacc = (tier == 1) ? (float*)(ws + 2 * xbytes + wbytes) : Zout;

  {
    int total = 2 * NB * PADT * NC;
    hipLaunchKernelGGL(zero_pads, dim3((total + 255) / 256), dim3(256), 0, stream,
                       Xbase, 2, strideSh);
  }
  hipLaunchKernelGGL(transpose_cast, dim3(64, 4, 16), dim3(256), 0, stream, ys, Xbase);
  hipLaunchKernelGGL(convert_w, dim3(8192), dim3(256), 0, stream, fw, gw, Ws);

  for (int l = 0; l < NLAYERS; ++l) {
    const short* Xin = (l & 1) ? Xbase + strideSh : Xbase;
    short* Xo       = (l & 1) ? Xbase : Xbase + strideSh;
    int writeX = (l < NLAYERS - 1) ? 1 : 0;
    int zmode;
    float* Zp;
    if (tier <= 2) {
      // pair-folded: even layers no Z traffic; odd layers fold z_{l-1} (Xin)
      zmode = (l & 1) ? ((l == 1) ? 1 : 2) : 0;
      Zp = Zacc;
    } else {
      zmode = (l == 0) ? 3 : 4;
      Zp = Zout;
    }
    hipLaunchKernelGGL(wavenet_layer, dim3(2, 16, 16), dim3(512), 0, stream,
                       Xin, Xo,
                       Ws + (size_t)l * MSTK * KTOT,
                       fb + l * NC, gb + l * NC, Zp, 1 << l, zmode, writeX);
  }

  if (tier == 1) {
    hipLaunchKernelGGL(transpose_out, dim3(64, 4, 16), dim3(256), 0, stream,
                       Zacc, Zout);
  } else if (tier == 2) {
    // Zacc lives in d_out; transpose into the freed X ping-pong area (fp32,
    // 69.2 MB >= 64 MB), then copy back to d_out.
    float* tmp = (float*)ws;
    hipLaunchKernelGGL(transpose_out, dim3(64, 4, 16), dim3(256), 0, stream,
                       Zacc, tmp);
    int n4 = (int)(zbytes / 16);
    hipLaunchKernelGGL(copy4, dim3(2048), dim3(256), 0, stream,
                       (const float4*)tmp, (float4*)Zout, n4);
  }
}

// Round 6
// 545.616 us; speedup vs baseline: 1.3972x; 1.2163x over previous
//
#include <hip/hip_runtime.h>

// WaveNet block: B=16, C=256, T=4096, LAYERS=8, K=2 (causal, dilation 2^l).
// Stacked single-GEMM per layer: filter+gate rows interleaved at 16-row
// granularity (M=512), N=B*T, K=512.
// r6 KEY: occupancy. Old 8-wave block: acc=128 AGPR + 120 VGPR = 248/wave
// -> 2 waves/SIMD -> ONE block/CU (measured Occ 20%) -> GEMM and epilogue
// phases serialized. New: BM=128(stk) x BN=128, 4 waves, wave-tile 64x64,
// acc=64 AGPR, LDS 32 KB -> 2-3 independent blocks/CU overlap phases.
// Counted-vmcnt double-buffered K-loop (never drains mid-loop), row-bit-2:1
// LDS swizzle, XCD swizzle groups same-X blocks per XCD.
// Z: tri-fold into fp32 Zacc[b][t][c] via 3-buffer round-robin X chain
// (folds x1+x2+x3 @l2, x4+x5+x6 @l5, x7+x8 @l7); final transpose kernel.

typedef __attribute__((ext_vector_type(8))) short s16x8;
typedef __attribute__((ext_vector_type(4))) short s16x4;
typedef __attribute__((ext_vector_type(4))) float f32x4;

#define NB 16
#define NC 256
#define NT 4096
#define TPAD 4224   // 128 (zero pad) + 4096
#define PADT 128
#define NLAYERS 8
#define KTOT 512    // C * Ktap
#define MSTK 512    // stacked rows: f/g interleaved at 16-row granularity

__device__ __forceinline__ short f2bf(float x) {
  union { float f; unsigned u; } v; v.f = x;
  unsigned u = v.u;
  unsigned r = (u + 0x7fffu + ((u >> 16) & 1u)) >> 16;  // RNE
  return (short)r;
}
__device__ __forceinline__ float bf2f(short s) {
  union { float f; unsigned u; } v; v.u = ((unsigned)(unsigned short)s) << 16;
  return v.f;
}

__device__ __forceinline__ void async16(short* lp, const short* gp) {
  __builtin_amdgcn_global_load_lds(
      (const __attribute__((address_space(1))) unsigned int*)gp,
      (__attribute__((address_space(3))) unsigned int*)lp,
      16, 0, 0);
}

// ---------------- prep kernels ----------------

// zero the t<0 pad region of nbuf consecutive X buffers (ws is poisoned 0xAA)
__global__ void zero_pads(short* __restrict__ base, int nbuf, size_t strideSh) {
  int idx = blockIdx.x * 256 + threadIdx.x;    // over nbuf * NB*PADT*NC
  if (idx >= nbuf * NB * PADT * NC) return;
  int j = idx >> 19;                            // / (NB*PADT*NC = 524288)
  int rem = idx & 524287;
  int b = rem >> 15;                            // / (PADT*NC)
  int r2 = rem & 32767;
  base[(size_t)j * strideSh + (size_t)b * TPAD * NC + r2] = 0;
}

// ys [b][c][t] fp32  ->  X0 [b][128+t][c] bf16 (LDS-tiled transpose)
__global__ void transpose_cast(const float* __restrict__ ys, short* __restrict__ X0) {
  __shared__ float tile[64][65];
  const int b = blockIdx.z, c0 = blockIdx.y * 64, t0 = blockIdx.x * 64;
  const int tid = threadIdx.x;
#pragma unroll
  for (int i = 0; i < 16; ++i) {
    int c = (tid >> 6) + i * 4;
    int t = tid & 63;
    tile[c][t] = ys[((size_t)(b * NC + c0 + c)) * NT + t0 + t];
  }
  __syncthreads();
#pragma unroll
  for (int i = 0; i < 2; ++i) {
    int q = tid + i * 256;                      // 512 chunks of 8 bf16
    int t = q >> 3, cc = (q & 7) * 8;
    s16x8 v;
#pragma unroll
    for (int j = 0; j < 8; ++j) v[j] = f2bf(tile[cc + j][t]);
    *(s16x8*)&X0[((size_t)(b * TPAD + PADT + t0 + t)) * NC + c0 + cc] = v;
  }
}

// weights [l][co][ci][kw] fp32 -> stacked interleaved Ws[l][r][k] bf16
// r = j*32 + s*16 + c16  (channel = j*16+c16, s: 0=filter 1=gate), k = kw*256+ci
__global__ void convert_w(const float* __restrict__ fw, const float* __restrict__ gw,
                          short* __restrict__ Ws) {
  int idx = blockIdx.x * 256 + threadIdx.x;     // over 8*512*512 = 2097152
  if (idx >= NLAYERS * MSTK * KTOT) return;
  int k = idx & (KTOT - 1);
  int r = (idx >> 9) & (MSTK - 1);
  int l = idx >> 18;
  int kw = k >> 8, ci = k & 255;
  int j = r >> 5, s = (r >> 4) & 1, c16 = r & 15;
  int ch = j * 16 + c16;
  int src = ((l * NC + ch) * NC + ci) * 2 + kw;
  Ws[idx] = f2bf(s ? gw[src] : fw[src]);
}

// ---------------- fused layer kernel ----------------
// grid (4, 32, 16): m-tile (64 channels, f+g stacked = 128 rows),
// t-tile (128), batch.  256 threads = 4 waves (2M x 2N), wave-tile 64x64.
// zmode: 0 = none; 1 = Zacc store; 2 = Zacc rmw.  Fold adds bf2f(Xin)
// (+ bf2f(Xprev) if non-null) to z before the Zacc op.
__global__ __launch_bounds__(256, 2)
void wavenet_layer(const short* __restrict__ Xin, short* __restrict__ Xout,
                   const short* __restrict__ Wl,
                   const float* __restrict__ bia_f, const float* __restrict__ bia_g,
                   float* __restrict__ Z, const short* __restrict__ Xprev,
                   int d, int zmode, int writeX) {
  __shared__ short lds[16384];                  // 32 KB: A0 A1 B0 B1 (8 KB each)

  const int tid = threadIdx.x;
  const int wave = tid >> 6, lane = tid & 63;
  const int quad = lane >> 4, l16 = lane & 15;
  const int wm = wave >> 1, wn = wave & 1;

  // XCD swizzle: give each XCD a contiguous logical range (= 2 batches,
  // all mt/ty) so same-X blocks share one L2 (~4.3 MB working set).
  int flat = blockIdx.x + 4 * (blockIdx.y + 32 * blockIdx.z);   // 0..2047
  int swz = (flat & 7) * 256 + (flat >> 3);                     // bijective
  const int mt = swz & 3;
  const int ty = (swz >> 2) & 31;
  const int b  = swz >> 7;
  const int m0s = mt * 128;                     // stacked-row base
  const int t0  = ty * 128;

  const short* Wm = Wl + (size_t)m0s * KTOT;
  const short* Xb = Xin + ((size_t)b * TPAD + PADT + t0) * NC;

  f32x4 acc[4][4] = {};
  // read-side swizzled chunk: row bits 2:1 (bit0 aliases the row-parity
  // bank bit and collapses a 16-lane phase group to 4 bank groups)
  const int xo = (quad ^ ((l16 >> 1) & 3)) * 8;

  // stage one BK=32 K-slab (A: 128x32, B: 128x32) into buffer `buf`
  auto STAGE = [&](int buf, int kk) {
    short* Ad = lds + buf * 4096;
    short* Bd = lds + 8192 + buf * 4096;
    const int kw = kk >> 3;
    const int ci0 = (kk & 7) * 32;
    const int k0 = kw * 256 + ci0;
    const int tsh = (kw == 0) ? -d : 0;         // tap 0 reads x[t-d]
#pragma unroll
    for (int i = 0; i < 2; ++i) {
      int q = i * 256 + tid;                    // physical chunk 0..511
      int r = q >> 2;                           // row 0..127
      int kc = ((q & 3) ^ ((r >> 1) & 3)) * 8;  // swizzled source chunk
      async16(Ad + q * 8, Wm + r * KTOT + k0 + kc);
      async16(Bd + q * 8, Xb + (r + tsh) * NC + ci0 + kc);   // tsh<0 ok
    }
  };

  // prologue: fill both buffers; wait only for buf0 (buf1 stays in flight)
  STAGE(0, 0);
  STAGE(1, 1);
  asm volatile("s_waitcnt vmcnt(4)" ::: "memory");
  __builtin_amdgcn_sched_barrier(0);
  __builtin_amdgcn_s_barrier();

  int cur = 0;
#pragma unroll 2
  for (int kk = 0; kk < 16; ++kk) {             // K = 512, BK = 32
    const short* Ar = lds + cur * 4096;
    const short* Br = lds + 8192 + cur * 4096;
    s16x8 bfr[4];
#pragma unroll
    for (int ni = 0; ni < 4; ++ni)
      bfr[ni] = *(const s16x8*)&Br[(wn * 64 + ni * 16 + l16) * 32 + xo];
    __builtin_amdgcn_s_setprio(1);
#pragma unroll
    for (int mi = 0; mi < 4; ++mi) {
      s16x8 af = *(const s16x8*)&Ar[(wm * 64 + mi * 16 + l16) * 32 + xo];
#pragma unroll
      for (int ni = 0; ni < 4; ++ni)
        acc[mi][ni] = __builtin_amdgcn_mfma_f32_16x16x32_bf16(af, bfr[ni], acc[mi][ni], 0, 0, 0);
    }
    __builtin_amdgcn_s_setprio(0);
    if (kk == 15) break;
    asm volatile("s_waitcnt lgkmcnt(0)" ::: "memory");
    __builtin_amdgcn_sched_barrier(0);
    __builtin_amdgcn_s_barrier();               // all waves done reading cur
    __builtin_amdgcn_sched_barrier(0);
    if (kk < 14) {
      STAGE(cur, kk + 2);                       // overwrite cur with slab kk+2
      asm volatile("s_waitcnt vmcnt(4)" ::: "memory");  // slab kk+1 landed
    } else {
      asm volatile("s_waitcnt vmcnt(0)" ::: "memory");  // tail: slab 15 landed
    }
    __builtin_amdgcn_sched_barrier(0);
    __builtin_amdgcn_s_barrier();               // cur^1 ready for all waves
    __builtin_amdgcn_sched_barrier(0);
    cur ^= 1;
  }
  __syncthreads();                              // all LDS reads done; reuse as ZT

  // ---------------- epilogue ----------------
  // mi even = filter rows, mi odd = gate rows of the SAME channels (in-thread).
  short* ZT = lds;                              // reuse: [128 t][64 c] rotated

#pragma unroll
  for (int p = 0; p < 2; ++p) {
    const int cloc = (wm * 2 + p) * 16 + quad * 4;   // local channel base 0..60
    const int ch = mt * 64 + cloc;                   // global channel base
    float4 bf4 = *(const float4*)&bia_f[ch];
    float4 bg4 = *(const float4*)&bia_g[ch];
    const float* bfp = (const float*)&bf4;
    const float* bgp = (const float*)&bg4;
#pragma unroll
    for (int ni = 0; ni < 4; ++ni) {
      const int tl = wn * 64 + ni * 16 + l16;        // tile-local time 0..127
      short pk[4];
#pragma unroll
      for (int r = 0; r < 4; ++r) {
        float f = acc[2 * p][ni][r] + bfp[r];
        float g = acc[2 * p + 1][ni][r] + bgp[r];
        float ef = __expf(2.f * f);
        float th = 1.f - 2.f / (ef + 1.f);           // tanh, no-overflow form
        float sg = 1.f / (1.f + __expf(-g));
        pk[r] = f2bf(th * sg);
      }
      // rotate-swizzle: physical col = (c + t*8) & 63 (stays 4-aligned)
      short* dst = &ZT[tl * 64 + ((cloc + tl * 8) & 63)];
      *(s16x4*)dst = (s16x4){pk[0], pk[1], pk[2], pk[3]};
    }
  }
  __syncthreads();
#pragma unroll
  for (int i = 0; i < 4; ++i) {                  // 1024 chunks of 16B (128 t rows)
    int q = tid + i * 256;
    int t = q >> 3, cc = (q & 7) * 8;
    s16x8 v = *(const s16x8*)&ZT[t * 64 + ((cc + t * 8) & 63)];
    const size_t xoff = ((size_t)(b * TPAD + PADT + t0 + t)) * NC + mt * 64 + cc;
    if (writeX) *(s16x8*)&Xout[xoff] = v;
    if (zmode) {
      // fold: z (+ Xin) (+ Xprev) into fp32 Zacc[b][t][c]
      s16x8 xv = *(const s16x8*)&Xin[xoff];
      float zv[8];
#pragma unroll
      for (int j = 0; j < 8; ++j) zv[j] = bf2f(v[j]) + bf2f(xv[j]);
      if (Xprev) {
        s16x8 pv = *(const s16x8*)&Xprev[xoff];
#pragma unroll
        for (int j = 0; j < 8; ++j) zv[j] += bf2f(pv[j]);
      }
      size_t zo = ((size_t)b * NT + t0 + t) * NC + mt * 64 + cc;
      if (zmode == 2) {
        float4 a0 = *(const float4*)&Z[zo];
        float4 a1 = *(const float4*)&Z[zo + 4];
        zv[0] += a0.x; zv[1] += a0.y; zv[2] += a0.z; zv[3] += a0.w;
        zv[4] += a1.x; zv[5] += a1.y; zv[6] += a1.z; zv[7] += a1.w;
      }
      *(float4*)&Z[zo]     = make_float4(zv[0], zv[1], zv[2], zv[3]);
      *(float4*)&Z[zo + 4] = make_float4(zv[4], zv[5], zv[6], zv[7]);
    }
  }
}

// ---------------- final: Zacc [b][t][c] fp32 -> dst [b][c][t] fp32 ----------------
__global__ void transpose_out(const float* __restrict__ src, float* __restrict__ dst) {
  __shared__ float tile[64][65];
  const int b = blockIdx.z, c0 = blockIdx.y * 64, t0 = blockIdx.x * 64;
  const int tid = threadIdx.x;
#pragma unroll
  for (int i = 0; i < 4; ++i) {
    int q = tid + i * 256;                      // 1024 float4 chunks
    int t = q >> 4, c = (q & 15) * 4;
    float4 v = *(const float4*)&src[((size_t)b * NT + t0 + t) * NC + c0 + c];
    tile[t][c] = v.x; tile[t][c + 1] = v.y; tile[t][c + 2] = v.z; tile[t][c + 3] = v.w;
  }
  __syncthreads();
#pragma unroll
  for (int i = 0; i < 4; ++i) {
    int q = tid + i * 256;
    int c = q >> 4, t = (q & 15) * 4;
    float4 v = make_float4(tile[t][c], tile[t + 1][c], tile[t + 2][c], tile[t + 3][c]);
    *(float4*)&dst[((size_t)b * NC + c0 + c) * NT + t0 + t] = v;
  }
}

__global__ void copy4(const float4* __restrict__ s, float4* __restrict__ d, int n) {
  int i = blockIdx.x * 256 + threadIdx.x;
  int stride = gridDim.x * 256;
  for (; i < n; i += stride) d[i] = s[i];
}

// ---------------- launch ----------------
extern "C" void kernel_launch(void* const* d_in, const int* in_sizes, int n_in,
                              void* d_out, int out_size, void* d_ws, size_t ws_size,
                              hipStream_t stream) {
  const float* ys = (const float*)d_in[0];
  const float* fw = (const float*)d_in[1];
  const float* fb = (const float*)d_in[2];
  const float* gw = (const float*)d_in[3];
  const float* gb = (const float*)d_in[4];
  float* Zout = (float*)d_out;

  char* ws = (char*)d_ws;
  const size_t xbytes = (size_t)NB * TPAD * NC * 2;      // 34.6 MB each
  const size_t strideSh = xbytes / 2;                    // shorts per X buffer
  const size_t wbytes = (size_t)NLAYERS * MSTK * KTOT * 2;   // 4.2 MB
  const size_t zbytes = (size_t)NB * NC * NT * 4;        // 64 MB fp32 Zacc

  // tier 1: 3 X bufs + Zacc in ws.  tier 2: 3 X bufs, Zacc on d_out.
  // tier 3: 2 X bufs (pair-fold), Zacc on d_out.
  int tier;
  if (ws_size >= 3 * xbytes + wbytes + zbytes)      tier = 1;
  else if (ws_size >= 3 * xbytes + wbytes)          tier = 2;
  else                                              tier = 3;

  const int nxb = (tier <= 2) ? 3 : 2;
  short* Xbase = (short*)ws;
  short* Ws = (short*)(ws + nxb * xbytes);
  float* Zacc = (tier == 1) ? (float*)(ws + 3 * xbytes + wbytes) : Zout;

  {
    int total = nxb * NB * PADT * NC;
    hipLaunchKernelGGL(zero_pads, dim3((total + 255) / 256), dim3(256), 0, stream,
                       Xbase, nxb, strideSh);
  }
  hipLaunchKernelGGL(transpose_cast, dim3(64, 4, 16), dim3(256), 0, stream, ys, Xbase);
  hipLaunchKernelGGL(convert_w, dim3(8192), dim3(256), 0, stream, fw, gw, Ws);

  for (int l = 0; l < NLAYERS; ++l) {
    const short* Xin;
    short* Xo;
    int zmode;
    const short* Xprev = nullptr;
    if (tier <= 2) {
      // 3-buffer round-robin: x_l in buf[l%3]
      Xin = Xbase + (size_t)(l % 3) * strideSh;
      Xo  = Xbase + (size_t)((l + 1) % 3) * strideSh;
      // tri-fold: l=2 -> {x1,x2,x3} store; l=5 -> {x4,x5,x6} rmw;
      //           l=7 -> {x7,x8} rmw.  x1 and x4 both live in buf1.
      if (l == 2)      { zmode = 1; Xprev = Xbase + strideSh; }
      else if (l == 5) { zmode = 2; Xprev = Xbase + strideSh; }
      else if (l == 7) { zmode = 2; }
      else             { zmode = 0; }
    } else {
      // 2-buffer ping-pong, pair-fold (r5 scheme): odd layers fold {x_l, x_{l+1}}
      Xin = (l & 1) ? Xbase + strideSh : Xbase;
      Xo  = (l & 1) ? Xbase : Xbase + strideSh;
      zmode = (l & 1) ? ((l == 1) ? 1 : 2) : 0;
    }
    int writeX = (l < NLAYERS - 1) ? 1 : 0;
    hipLaunchKernelGGL(wavenet_layer, dim3(4, 32, 16), dim3(256), 0, stream,
                       Xin, Xo,
                       Ws + (size_t)l * MSTK * KTOT,
                       fb + l * NC, gb + l * NC, Zacc, Xprev,
                       1 << l, zmode, writeX);
  }

  if (tier == 1) {
    hipLaunchKernelGGL(transpose_out, dim3(64, 4, 16), dim3(256), 0, stream,
                       Zacc, Zout);
  } else {
    // Zacc lives in d_out; transpose into the freed X area (fp32, 64 MB fits
    // in the first two X buffers = 69 MB), then copy back to d_out.
    float* tmp = (float*)ws;
    hipLaunchKernelGGL(transpose_out, dim3(64, 4, 16), dim3(256), 0, stream,
                       Zacc, tmp);
    int n4 = (int)(zbytes / 16);
    hipLaunchKernelGGL(copy4, dim3(2048), dim3(256), 0, stream,
                       (const float4*)tmp, (float4*)Zout, n4);
  }
}